// Round 8
// baseline (4994.628 us; speedup 1.0000x reference)
//
#include <hip/hip_runtime.h>
#include <math.h>

#define NEG10K -10000.0f
// K=12 tags, START=10, STOP=11, B=64, T=1024, V=50000, D=256, Hh=256, 4Hh=1024

// ---------------- workspace layout (float offsets) ----------------
static const size_t OFF_WT_IH = 0;                  // [2][256][1024]  Wih^T per dir
static const size_t OFF_WT_HH = 524288;             // [2][256][1024]  Whh^T per dir
static const size_t OFF_BIAS  = 1048576;            // [2][1024]       bih+bhh
static const size_t OFF_WTAGD = 1050624;            // [2][16][256]    Wtag halves, k-padded to 16
static const size_t OFF_BTAG  = 1058816;            // [16]
static const size_t OFF_FEATS = 1058832;            // [2][64][1024][16] per-dir partial feats
static const size_t OFF_HC    = 3155984;            // [2][64][256] (unused in 1-dispatch path)
static const size_t OFF_CC    = 3188752;            // [2][64][256] (unused in 1-dispatch path)
static const size_t OFF_PUB   = 3221520;            // [2 parity][128 dirbatch][256] u64 (tag<<32|h)
static const size_t OFF_END   = 3352592;            // workspace floor for split path

__device__ __forceinline__ float sigf(float x) { return 1.0f / (1.0f + expf(-x)); }

// ---------------- weight transposes: [1024][256] -> [256][1024] ----------------
__global__ __launch_bounds__(256) void k_transpose(
    const float* __restrict__ wih_f, const float* __restrict__ wih_b,
    const float* __restrict__ whh_f, const float* __restrict__ whh_b,
    float* __restrict__ ws) {
  __shared__ float tile[32][33];
  int z = blockIdx.z;
  const float* src = (z == 0) ? wih_f : (z == 1) ? wih_b : (z == 2) ? whh_f : whh_b;
  float* dst = ws + ((z < 2) ? (OFF_WT_IH + (size_t)z * 262144)
                             : (OFF_WT_HH + (size_t)(z - 2) * 262144));
  int r0 = blockIdx.y * 32;  // over 1024 rows of src
  int c0 = blockIdx.x * 32;  // over 256 cols of src
  int tid = threadIdx.x;
  int c = tid & 31, rg = tid >> 5;
#pragma unroll
  for (int i = 0; i < 4; ++i) {
    int r = rg * 4 + i;
    tile[r][c] = src[(size_t)(r0 + r) * 256 + c0 + c];
  }
  __syncthreads();
  int r2 = tid & 31, cg = tid >> 5;
#pragma unroll
  for (int i = 0; i < 4; ++i) {
    int ccv = cg * 4 + i;
    dst[(size_t)(c0 + ccv) * 1024 + r0 + r2] = tile[r2][ccv];
  }
}

// ---- small prep: bias combine, Wtag halves, btag pad, pub-buffer zero (tag safety) ----
__global__ __launch_bounds__(256) void k_prep_small(
    const float* __restrict__ bih_f, const float* __restrict__ bhh_f,
    const float* __restrict__ bih_b, const float* __restrict__ bhh_b,
    const float* __restrict__ wtag, const float* __restrict__ btag,
    float* __restrict__ ws) {
  int i = blockIdx.x * 256 + threadIdx.x;
  if (i < 2048) {
    int d = i >> 10, n = i & 1023;
    ws[OFF_BIAS + i] = d ? (bih_b[n] + bhh_b[n]) : (bih_f[n] + bhh_f[n]);
  } else if (i < 2048 + 8192) {
    int r = i - 2048;
    int d = r >> 12, rem = r & 4095;
    int k = rem >> 8, j = rem & 255;
    ws[OFF_WTAGD + r] = (k < 12) ? wtag[(size_t)k * 512 + d * 256 + j] : 0.0f;
  } else if (i < 2048 + 8192 + 16) {
    int kk = i - 10240;
    ws[OFF_BTAG + kk] = (kk < 12) ? btag[kk] : 0.0f;
  } else if (i < 10256 + 131072) {
    ws[OFF_PUB + (i - 10256)] = 0.0f;  // zero tags: no false-match vs any step tag
  }
}

// ---------------- fused recurrent LSTM: 16-way unit-split, 2 WGs/CU for TLP ----------------
// 512 WGs x 256 thr (4 waves) = 32 groups x 16 slices; group = (dir, 4 batches),
// slice owns 16 units. ~74 KB LDS/WG -> exactly 2 WGs/CU: one WG's FMA stream
// covers the other's barrier/RTT/gates stalls (independent barrier domains).
// Per-thread schedule identical to R6: 16-k slice, 4 cols, wh[16]/wi[16] f4,
// x-proj in the gather-RTT shadow. Exchange protocol (tag-in-data u64, parity
// ping-pong, poll-after-S3 pacing, concurrent polls -- now 4/thread) unchanged.
#define FMA4(A, W, S) { A.x = fmaf(W.x, S, A.x); A.y = fmaf(W.y, S, A.y); \
                        A.z = fmaf(W.z, S, A.z); A.w = fmaf(W.w, S, A.w); }
__global__ __launch_bounds__(256, 2) void k_lstm_split(
    const float* __restrict__ ws_c, const int* __restrict__ sentence,
    const float* __restrict__ emb, const float* __restrict__ h0p,
    const float* __restrict__ c0p, const int* __restrict__ seq_lens,
    float* __restrict__ ws_mut, int first) {
  __shared__ float zpart[4][4][64];   // 4 KB: per-wave k-partials
  __shared__ float zs[4][64];         // 1 KB: summed z + bias
  __shared__ float h_s[4][256];       // 4 KB: gathered full h
  __shared__ float x_s[2][4][256];    // 8 KB: ping-pong emb rows
  __shared__ int   sent_s[4][1024];   // 16 KB: token ids for the quad
  __shared__ float wt_s[16][260];     // 16.25 KB: Wtag half (padded, w==0 use)
  __shared__ float ldspad[6400];      // 25 KB pad -> ~74.5 KB total, 2 WGs/CU

  int bx = blockIdx.x;
  int w   = (bx >> 3) & 15;                // slice 0..15 (16 units each)
  int gid = (bx & 7) + ((bx >> 7) << 3);   // group 0..31; a group's slices share an XCD
  int d   = gid >> 4;                      // dir
  int bq4 = (gid & 15) * 4;                // first batch of the quad
  int u0  = w * 16;                        // first owned unit
  int tid = threadIdx.x;                   // 0..255
  int ln  = tid & 63;
  if (first == 777) {  // opaque: keeps ldspad allocated, never taken at runtime
    ldspad[tid] = (float)tid; __syncthreads(); zs[0][0] = ldspad[tid ^ 1];
  }

  int cg = tid & 15, kq = tid >> 4;   // phase-A mapping: 16 col-groups x 16 k-slices
  int c4 = cg * 4;
  int wv = tid >> 6;                  // wave 0..3

  for (int i = tid; i < 4096; i += 256)
    sent_s[i >> 10][i & 1023] = sentence[(size_t)(bq4 + (i >> 10)) * 1024 + (i & 1023)];
  for (int i = tid; i < 4096; i += 256)
    wt_s[i >> 8][i & 255] = ws_c[OFF_WTAGD + (size_t)d * 4096 + i];
  __syncthreads();  // sent_s ready

  // ---- Whh + Wih slices into registers: 16 float4 each, fixed across all steps ----
  const float* WhhT = ws_c + OFF_WT_HH + (size_t)d * 262144;  // [256][1024]
  const float* WihT = ws_c + OFF_WT_IH + (size_t)d * 262144;
  int wcol = (cg >> 2) * 256 + u0 + (cg & 3) * 4;
  float4 wh[16], wi[16];
#pragma unroll
  for (int i = 0; i < 16; ++i) {
    wh[i] = *(const float4*)(WhhT + (size_t)(kq * 16 + i) * 1024 + wcol);
    wi[i] = *(const float4*)(WihT + (size_t)(kq * 16 + i) * 1024 + wcol);
  }

  for (int i = tid; i < 1024; i += 256)
    h_s[i >> 8][i & 255] = h0p[((size_t)d * 64 + bq4 + (i >> 8)) * 256 + (i & 255)];
  float cc = 0.0f; int mylen = 0;
  int ob = tid >> 4, ou = tid & 15;  // owner mapping (tid<64): (batch, owned unit)
  if (tid < 64) {
    cc = c0p[((size_t)d * 64 + bq4 + ob) * 256 + u0 + ou];
    mylen = seq_lens[bq4 + ob];
  }
  // phase-B col + bias (fixed per thread): local col jB in [0,64)
  int bB = tid >> 6, jB = tid & 63;
  float biasB = ws_c[OFF_BIAS + (size_t)d * 1024 + (jB >> 4) * 256 + u0 + (jB & 15)];
  // x-load mapping: thread loads float4 of batch xb's emb row
  int xb = tid >> 6, xj = (tid & 63) * 4;
  {
    int tt = d ? 1023 : 0;
    *(float4*)&x_s[0][xb][xj] = *(const float4*)(emb + (size_t)sent_s[xb][tt] * 256 + xj);
  }
  unsigned long long* pub64 = (unsigned long long*)(ws_mut + OFF_PUB);
  float* featsD = ws_mut + OFF_FEATS + (size_t)d * 1048576;
  bool bail = false;
  __syncthreads();  // h_s, x_s[0] ready

  // ---- pre-loop: x-projection partial for step 0 ----
  float4 acc_carry[4] = {{0,0,0,0},{0,0,0,0},{0,0,0,0},{0,0,0,0}};
#pragma unroll
  for (int i = 0; i < 4; ++i) {
    int k = kq * 16 + i * 4;
    float4 q0 = wi[i * 4], q1 = wi[i * 4 + 1], q2 = wi[i * 4 + 2], q3 = wi[i * 4 + 3];
#pragma unroll
    for (int b = 0; b < 4; ++b) {
      float4 xv = *(const float4*)&x_s[0][b][k];
      FMA4(acc_carry[b], q0, xv.x); FMA4(acc_carry[b], q1, xv.y);
      FMA4(acc_carry[b], q2, xv.z); FMA4(acc_carry[b], q3, xv.w);
    }
  }

  for (int s = 0; s < 1024; ++s) {
    int t = d ? (1023 - s) : s;
    int p = s & 1;
    int nxt = (s & 1) ^ 1;
    unsigned tag = (unsigned)(s + 1);
    // issue emb prefetch for step s+1 (consumed in phase B write; phase-A cover)
    float4 xpf;
    {
      int sn = (s + 1 < 1024) ? (s + 1) : s;
      int tn = d ? (1023 - sn) : sn;
      xpf = *(const float4*)(emb + (size_t)sent_s[xb][tn] * 256 + xj);
    }
    // ---- phase A: h-recurrence partials on top of the x-part (acc_carry) ----
    float4 acc[4];
#pragma unroll
    for (int b = 0; b < 4; ++b) acc[b] = acc_carry[b];
#pragma unroll
    for (int i = 0; i < 4; ++i) {
      int k = kq * 16 + i * 4;
      float4 w0 = wh[i * 4], w1 = wh[i * 4 + 1], w2 = wh[i * 4 + 2], w3 = wh[i * 4 + 3];
#pragma unroll
      for (int b = 0; b < 4; ++b) {
        float4 hv = *(const float4*)&h_s[b][k];
        FMA4(acc[b], w0, hv.x); FMA4(acc[b], w1, hv.y);
        FMA4(acc[b], w2, hv.z); FMA4(acc[b], w3, hv.w);
      }
    }
#pragma unroll
    for (int b = 0; b < 4; ++b) {  // fold the 4 k-slices within each wave
      acc[b].x += __shfl_xor(acc[b].x, 16);
      acc[b].y += __shfl_xor(acc[b].y, 16);
      acc[b].z += __shfl_xor(acc[b].z, 16);
      acc[b].w += __shfl_xor(acc[b].w, 16);
      acc[b].x += __shfl_xor(acc[b].x, 32);
      acc[b].y += __shfl_xor(acc[b].y, 32);
      acc[b].z += __shfl_xor(acc[b].z, 32);
      acc[b].w += __shfl_xor(acc[b].w, 32);
    }
    if ((tid & 48) == 0) {
#pragma unroll
      for (int b = 0; b < 4; ++b) *(float4*)&zpart[wv][b][c4] = acc[b];
    }
    __syncthreads();  // S1
    // ---- phase B: fold 4 wave-partials + bias; stage next x into x_s ----
    zs[bB][jB] = zpart[0][bB][jB] + zpart[1][bB][jB] + zpart[2][bB][jB] + zpart[3][bB][jB] +
                 biasB;
    *(float4*)&x_s[nxt][xb][xj] = xpf;
    __syncthreads();  // S2
    // ---- phase C: owners update c/h; publish (tag|h) u64 ----
    if (tid < 64) {
      float zi = zs[ob][ou], zf = zs[ob][16 + ou], zg = zs[ob][32 + ou], zo = zs[ob][48 + ou];
      float cn = sigf(zf) * cc + sigf(zi) * tanhf(zg);
      float hn = sigf(zo) * tanhf(cn);
      bool m = t < mylen;
      cc = m ? cn : cc;
      float hp = m ? hn : h_s[ob][u0 + ou];
      union { float f; unsigned u; } hb; hb.f = hp;
      unsigned long long pk = ((unsigned long long)tag << 32) | (unsigned long long)hb.u;
      __hip_atomic_store(
          pub64 + (size_t)p * 32768 + ((size_t)d * 64 + bq4 + ob) * 256 + (u0 + ou),
          pk, __ATOMIC_RELAXED, __HIP_MEMORY_SCOPE_AGENT);
    }
    // ---- publish shadow: tag head for step s-1 (w==0 slice only) ----
    if (w == 0 && s > 0) {
      int tp = d ? (1023 - (s - 1)) : (s - 1);
#pragma unroll
      for (int half = 0; half < 2; ++half) {
        int vs = wv + 4 * half;             // virtual 8-slot layout as in R5
        int tb_b = vs >> 1;
        int tb_k = (vs & 1) * 8 + (ln >> 3);
        int tb_j = ln & 7;
        float pv = 0.0f;
#pragma unroll
        for (int i = 0; i < 32; ++i)
          pv = fmaf(h_s[tb_b][tb_j + 8 * i], wt_s[tb_k][tb_j + 8 * i], pv);
        pv += __shfl_xor(pv, 1);
        pv += __shfl_xor(pv, 2);
        pv += __shfl_xor(pv, 4);
        if (tb_j == 0)
          featsD[(size_t)(bq4 + tb_b) * 16384 + (size_t)tp * 16 + tb_k] = pv;
      }
    }
    __syncthreads();  // S3: tag-head reads of h_s done before gather overwrites
    // ---- gather: issue 4 concurrent poll loads, fill RTT with x-proj, then poll ----
    {
      size_t base = (size_t)p * 32768 + ((size_t)d * 64 + bq4) * 256 + tid;
      unsigned long long v0 =
          __hip_atomic_load(pub64 + base,       __ATOMIC_RELAXED, __HIP_MEMORY_SCOPE_AGENT);
      unsigned long long v1 =
          __hip_atomic_load(pub64 + base + 256, __ATOMIC_RELAXED, __HIP_MEMORY_SCOPE_AGENT);
      unsigned long long v2 =
          __hip_atomic_load(pub64 + base + 512, __ATOMIC_RELAXED, __HIP_MEMORY_SCOPE_AGENT);
      unsigned long long v3 =
          __hip_atomic_load(pub64 + base + 768, __ATOMIC_RELAXED, __HIP_MEMORY_SCOPE_AGENT);
      if (s + 1 < 1024) {  // x-projection for step s+1 from x_s[nxt], in the RTT shadow
#pragma unroll
        for (int b = 0; b < 4; ++b) { acc_carry[b].x = 0; acc_carry[b].y = 0;
                                      acc_carry[b].z = 0; acc_carry[b].w = 0; }
#pragma unroll
        for (int i = 0; i < 4; ++i) {
          int k = kq * 16 + i * 4;
          float4 q0 = wi[i * 4], q1 = wi[i * 4 + 1], q2 = wi[i * 4 + 2], q3 = wi[i * 4 + 3];
#pragma unroll
          for (int b = 0; b < 4; ++b) {
            float4 xv = *(const float4*)&x_s[nxt][b][k];
            FMA4(acc_carry[b], q0, xv.x); FMA4(acc_carry[b], q1, xv.y);
            FMA4(acc_carry[b], q2, xv.z); FMA4(acc_carry[b], q3, xv.w);
          }
        }
      }
      unsigned spin = 0;
      while ((((unsigned)(v0 >> 32) != tag) || ((unsigned)(v1 >> 32) != tag) ||
              ((unsigned)(v2 >> 32) != tag) || ((unsigned)(v3 >> 32) != tag)) && !bail) {
        __builtin_amdgcn_s_sleep(1);
        if ((unsigned)(v0 >> 32) != tag)
          v0 = __hip_atomic_load(pub64 + base,       __ATOMIC_RELAXED, __HIP_MEMORY_SCOPE_AGENT);
        if ((unsigned)(v1 >> 32) != tag)
          v1 = __hip_atomic_load(pub64 + base + 256, __ATOMIC_RELAXED, __HIP_MEMORY_SCOPE_AGENT);
        if ((unsigned)(v2 >> 32) != tag)
          v2 = __hip_atomic_load(pub64 + base + 512, __ATOMIC_RELAXED, __HIP_MEMORY_SCOPE_AGENT);
        if ((unsigned)(v3 >> 32) != tag)
          v3 = __hip_atomic_load(pub64 + base + 768, __ATOMIC_RELAXED, __HIP_MEMORY_SCOPE_AGENT);
        if (++spin > 2000000u) { bail = true; break; }  // sticky escape: finite fail
      }
      union { unsigned u32; float f; } cv;
      cv.u32 = (unsigned)v0; h_s[0][tid] = cv.f;
      cv.u32 = (unsigned)v1; h_s[1][tid] = cv.f;
      cv.u32 = (unsigned)v2; h_s[2][tid] = cv.f;
      cv.u32 = (unsigned)v3; h_s[3][tid] = cv.f;
    }
    __syncthreads();  // S4
  }
  // drain: tag head for the last step from final gathered h (w==0 slice only)
  if (w == 0) {
    int tl = d ? 0 : 1023;
#pragma unroll
    for (int half = 0; half < 2; ++half) {
      int vs = wv + 4 * half;
      int tb_b = vs >> 1;
      int tb_k = (vs & 1) * 8 + (ln >> 3);
      int tb_j = ln & 7;
      float pv = 0.0f;
#pragma unroll
      for (int i = 0; i < 32; ++i)
        pv = fmaf(h_s[tb_b][tb_j + 8 * i], wt_s[tb_k][tb_j + 8 * i], pv);
      pv += __shfl_xor(pv, 1);
      pv += __shfl_xor(pv, 2);
      pv += __shfl_xor(pv, 4);
      if (tb_j == 0)
        featsD[(size_t)(bq4 + tb_b) * 16384 + (size_t)tl * 16 + tb_k] = pv;
    }
  }
}

// ---------------- fallback fused LSTM (round-2, known-good; tiny-workspace path) ----------------
__global__ __launch_bounds__(256) void k_lstm_fused(
    const float* __restrict__ ws_c, const int* __restrict__ sentence,
    const float* __restrict__ emb, const float* __restrict__ h0p,
    const float* __restrict__ c0p, const int* __restrict__ seq_lens,
    float* __restrict__ ws_mut) {
  int d = blockIdx.x & 1;
  int pr = blockIdx.x >> 1;
  int b0 = pr * 2, b1 = b0 + 1;
  const float* Wih = ws_c + OFF_WT_IH + (size_t)d * 262144;
  const float* Whh = ws_c + OFF_WT_HH + (size_t)d * 262144;
  __shared__ float h_s[2][256];
  __shared__ float x_s[2][2][256];
  __shared__ float z_s[2][1024];
  __shared__ int   sent_s[2][1024];
  __shared__ float wt_s[16][260];
  __shared__ float pfp_s[2][16][8];
  int tid = threadIdx.x;
  int len0 = seq_lens[b0], len1 = seq_lens[b1];
  for (int i = tid; i < 2048; i += 256)
    sent_s[i >> 10][i & 1023] = sentence[(size_t)(b0 + (i >> 10)) * 1024 + (i & 1023)];
  for (int i = tid; i < 4096; i += 256)
    wt_s[i >> 8][i & 255] = ws_c[OFF_WTAGD + (size_t)d * 4096 + i];
  h_s[0][tid] = h0p[((size_t)d * 64 + b0) * 256 + tid];
  h_s[1][tid] = h0p[((size_t)d * 64 + b1) * 256 + tid];
  float cc0 = c0p[((size_t)d * 64 + b0) * 256 + tid];
  float cc1 = c0p[((size_t)d * 64 + b1) * 256 + tid];
  int c4 = tid * 4;
  float4 bias_v = *(const float4*)(ws_c + OFF_BIAS + (size_t)d * 1024 + c4);
  __syncthreads();
  int t0 = d ? 1023 : 0;
  if (tid < 128) {
    int bb = tid >> 6, l = tid & 63;
    int row = sent_s[bb][t0];
    *(float4*)&x_s[0][bb][l * 4] = *(const float4*)(emb + (size_t)row * 256 + l * 4);
  }
  __syncthreads();
  float* featsD = ws_mut + OFF_FEATS + (size_t)d * 1048576;
  for (int s = 0; s < 1024; ++s) {
    int t = d ? (1023 - s) : s;
    int cur = s & 1, nxt = cur ^ 1;
    float4 pf = {0, 0, 0, 0};
    if (tid < 128) {
      int sn = (s < 1023) ? (s + 1) : 1023;
      int tn = d ? (1023 - sn) : sn;
      int bb = tid >> 6, l = tid & 63;
      pf = *(const float4*)(emb + (size_t)sent_s[bb][tn] * 256 + l * 4);
    }
    float4 a0 = bias_v, a1 = bias_v;
#pragma unroll 4
    for (int k = 0; k < 256; k += 4) {
      float4 xv0 = *(const float4*)&x_s[cur][0][k];
      float4 xv1 = *(const float4*)&x_s[cur][1][k];
      float4 hv0 = *(const float4*)&h_s[0][k];
      float4 hv1 = *(const float4*)&h_s[1][k];
      const float* wi = Wih + (size_t)k * 1024 + c4;
      const float* wh = Whh + (size_t)k * 1024 + c4;
      float4 wi0 = *(const float4*)(wi);
      float4 wi1 = *(const float4*)(wi + 1024);
      float4 wi2 = *(const float4*)(wi + 2048);
      float4 wi3 = *(const float4*)(wi + 3072);
      float4 wh0 = *(const float4*)(wh);
      float4 wh1 = *(const float4*)(wh + 1024);
      float4 wh2 = *(const float4*)(wh + 2048);
      float4 wh3 = *(const float4*)(wh + 3072);
      FMA4(a0, wi0, xv0.x); FMA4(a0, wi1, xv0.y); FMA4(a0, wi2, xv0.z); FMA4(a0, wi3, xv0.w);
      FMA4(a0, wh0, hv0.x); FMA4(a0, wh1, hv0.y); FMA4(a0, wh2, hv0.z); FMA4(a0, wh3, hv0.w);
      FMA4(a1, wi0, xv1.x); FMA4(a1, wi1, xv1.y); FMA4(a1, wi2, xv1.z); FMA4(a1, wi3, xv1.w);
      FMA4(a1, wh0, hv1.x); FMA4(a1, wh1, hv1.y); FMA4(a1, wh2, hv1.z); FMA4(a1, wh3, hv1.w);
    }
    *(float4*)&z_s[0][c4] = a0;
    *(float4*)&z_s[1][c4] = a1;
    __syncthreads();
    {
      float iv = z_s[0][tid], fv = z_s[0][tid + 256];
      float gv = z_s[0][tid + 512], ov = z_s[0][tid + 768];
      float cn = sigf(fv) * cc0 + sigf(iv) * tanhf(gv);
      float hn = sigf(ov) * tanhf(cn);
      bool m = t < len0;
      cc0 = m ? cn : cc0;
      h_s[0][tid] = m ? hn : h_s[0][tid];
    }
    {
      float iv = z_s[1][tid], fv = z_s[1][tid + 256];
      float gv = z_s[1][tid + 512], ov = z_s[1][tid + 768];
      float cn = sigf(fv) * cc1 + sigf(iv) * tanhf(gv);
      float hn = sigf(ov) * tanhf(cn);
      bool m = t < len1;
      cc1 = m ? cn : cc1;
      h_s[1][tid] = m ? hn : h_s[1][tid];
    }
    if (tid < 128) {
      int bb = tid >> 6, l = tid & 63;
      *(float4*)&x_s[nxt][bb][l * 4] = pf;
    }
    __syncthreads();
    {
      int b2 = tid >> 7, r = tid & 127;
      int ks = r >> 3, jg = r & 7;
      const float* hv = &h_s[b2][jg * 32];
      const float* wv = &wt_s[ks][jg * 32];
      float p = 0.0f;
#pragma unroll
      for (int i = 0; i < 32; ++i) p = fmaf(hv[i], wv[i], p);
      pfp_s[b2][ks][jg] = p;
    }
    __syncthreads();
    if (tid < 32) {
      int b = tid >> 4, k = tid & 15;
      float sum = 0.0f;
#pragma unroll
      for (int i = 0; i < 8; ++i) sum += pfp_s[b][k][i];
      featsD[(size_t)(b0 + b) * 16384 + (size_t)t * 16 + k] = sum;
    }
  }
}

// ---------------- Viterbi + backtrace, one wave per batch element ----------------
__global__ __launch_bounds__(64) void k_viterbi(const float* __restrict__ ws_c,
                                                const float* __restrict__ trans,
                                                const int* __restrict__ seq_lens,
                                                float* __restrict__ out) {
  __shared__ char bp_s[1024][12];
  int b = blockIdx.x, lane = threadIdx.x;
  int len = seq_lens[b];
  float trow[12];
#pragma unroll
  for (int p = 0; p < 12; ++p) trow[p] = (lane < 12) ? trans[lane * 12 + p] : 0.0f;
  float tb = (lane < 16) ? ws_c[OFF_BTAG + lane] : 0.0f;
  float fv = (lane == 10) ? 0.0f : NEG10K;  // START=10
  const float* ff = ws_c + OFF_FEATS + (size_t)b * 16384;
  const float* fb = ws_c + OFF_FEATS + 1048576 + (size_t)b * 16384;
  for (int t = 0; t < 1024; ++t) {
    float ft = (lane < 16) ? (ff[t * 16 + lane] + fb[t * 16 + lane] + tb) : 0.0f;
    float best = -3.0e38f; int arg = 0;
#pragma unroll
    for (int p = 0; p < 12; ++p) {
      float s = __shfl(fv, p) + trow[p];
      if (s > best) { best = s; arg = p; }
    }
    bool m = t < len;
    if (m) fv = best + ft;
    if (lane < 12) bp_s[t][lane] = (char)(m ? arg : lane);
  }
  float term = (lane < 12) ? fv + trans[132 + lane] : -3.0e38f;  // STOP row = 11
  float bestv = -3.0e38f; int bestp = 0;
#pragma unroll
  for (int p = 0; p < 12; ++p) {
    float v = __shfl(term, p);
    if (v > bestv) { bestv = v; bestp = p; }
  }
  __syncthreads();
  if (lane == 0) {
    out[b] = bestv;
    int tag = bestp;
    float* po = out + 64 + (size_t)b * 1024;
    for (int t = 1023; t >= 0; --t) {
      po[t] = (t < len) ? (float)tag : 0.0f;
      tag = bp_s[t][tag];
    }
  }
}

extern "C" void kernel_launch(void* const* d_in, const int* in_sizes, int n_in,
                              void* d_out, int out_size, void* d_ws, size_t ws_size,
                              hipStream_t stream) {
  (void)in_sizes; (void)n_in; (void)out_size;
  const int*   sentence = (const int*)d_in[0];
  const int*   seq_lens = (const int*)d_in[1];
  const float* emb      = (const float*)d_in[2];
  const float* wih_f    = (const float*)d_in[3];
  const float* whh_f    = (const float*)d_in[4];
  const float* bih_f    = (const float*)d_in[5];
  const float* bhh_f    = (const float*)d_in[6];
  const float* wih_b    = (const float*)d_in[7];
  const float* whh_b    = (const float*)d_in[8];
  const float* bih_b    = (const float*)d_in[9];
  const float* bhh_b    = (const float*)d_in[10];
  const float* wtag     = (const float*)d_in[11];
  const float* btag     = (const float*)d_in[12];
  const float* trans    = (const float*)d_in[13];
  const float* h0p      = (const float*)d_in[14];
  const float* c0p      = (const float*)d_in[15];
  float* ws  = (float*)d_ws;
  float* out = (float*)d_out;
  size_t avail = ws_size / 4;
  if (avail < OFF_FEATS + 2097152) return;  // below even the fused path's needs

  k_transpose<<<dim3(8, 32, 4), 256, 0, stream>>>(wih_f, wih_b, whh_f, whh_b, ws);
  k_prep_small<<<553, 256, 0, stream>>>(bih_f, bhh_f, bih_b, bhh_b, wtag, btag, ws);
  if (avail >= OFF_END) {
    k_lstm_split<<<512, 256, 0, stream>>>(ws, sentence, emb, h0p, c0p, seq_lens, ws, 1);
  } else {
    k_lstm_fused<<<64, 256, 0, stream>>>(ws, sentence, emb, h0p, c0p, seq_lens, ws);
  }
  k_viterbi<<<64, 64, 0, stream>>>(ws, trans, seq_lens, out);
}

// Round 9
// 3628.132 us; speedup vs baseline: 1.3766x; 1.3766x over previous
//
#include <hip/hip_runtime.h>
#include <math.h>

#define NEG10K -10000.0f
// K=12 tags, START=10, STOP=11, B=64, T=1024, V=50000, D=256, Hh=256, 4Hh=1024

// ---------------- workspace layout (float offsets) ----------------
static const size_t OFF_WT_IH = 0;                  // [2][256][1024]  Wih^T per dir
static const size_t OFF_WT_HH = 524288;             // [2][256][1024]  Whh^T per dir
static const size_t OFF_BIAS  = 1048576;            // [2][1024]       bih+bhh
static const size_t OFF_WTAGD = 1050624;            // [2][16][256]    Wtag halves, k-padded to 16
static const size_t OFF_BTAG  = 1058816;            // [16]
static const size_t OFF_FEATS = 1058832;            // [2][64][1024][16] per-dir partial feats
static const size_t OFF_HC    = 3155984;            // [2][64][256] (unused in 1-dispatch path)
static const size_t OFF_CC    = 3188752;            // [2][64][256] (unused in 1-dispatch path)
static const size_t OFF_PUB   = 3221520;            // [2 parity][128 dirbatch][256] u64 (tag<<32|h)
static const size_t OFF_END   = 3352592;            // workspace floor for split path

__device__ __forceinline__ float sigf(float x) { return 1.0f / (1.0f + expf(-x)); }

// ---------------- weight transposes: [1024][256] -> [256][1024] ----------------
__global__ __launch_bounds__(256) void k_transpose(
    const float* __restrict__ wih_f, const float* __restrict__ wih_b,
    const float* __restrict__ whh_f, const float* __restrict__ whh_b,
    float* __restrict__ ws) {
  __shared__ float tile[32][33];
  int z = blockIdx.z;
  const float* src = (z == 0) ? wih_f : (z == 1) ? wih_b : (z == 2) ? whh_f : whh_b;
  float* dst = ws + ((z < 2) ? (OFF_WT_IH + (size_t)z * 262144)
                             : (OFF_WT_HH + (size_t)(z - 2) * 262144));
  int r0 = blockIdx.y * 32;  // over 1024 rows of src
  int c0 = blockIdx.x * 32;  // over 256 cols of src
  int tid = threadIdx.x;
  int c = tid & 31, rg = tid >> 5;
#pragma unroll
  for (int i = 0; i < 4; ++i) {
    int r = rg * 4 + i;
    tile[r][c] = src[(size_t)(r0 + r) * 256 + c0 + c];
  }
  __syncthreads();
  int r2 = tid & 31, cg = tid >> 5;
#pragma unroll
  for (int i = 0; i < 4; ++i) {
    int ccv = cg * 4 + i;
    dst[(size_t)(c0 + ccv) * 1024 + r0 + r2] = tile[r2][ccv];
  }
}

// ---- small prep: bias combine, Wtag halves, btag pad, pub-buffer zero (tag safety) ----
__global__ __launch_bounds__(256) void k_prep_small(
    const float* __restrict__ bih_f, const float* __restrict__ bhh_f,
    const float* __restrict__ bih_b, const float* __restrict__ bhh_b,
    const float* __restrict__ wtag, const float* __restrict__ btag,
    float* __restrict__ ws) {
  int i = blockIdx.x * 256 + threadIdx.x;
  if (i < 2048) {
    int d = i >> 10, n = i & 1023;
    ws[OFF_BIAS + i] = d ? (bih_b[n] + bhh_b[n]) : (bih_f[n] + bhh_f[n]);
  } else if (i < 2048 + 8192) {
    int r = i - 2048;
    int d = r >> 12, rem = r & 4095;
    int k = rem >> 8, j = rem & 255;
    ws[OFF_WTAGD + r] = (k < 12) ? wtag[(size_t)k * 512 + d * 256 + j] : 0.0f;
  } else if (i < 2048 + 8192 + 16) {
    int kk = i - 10240;
    ws[OFF_BTAG + kk] = (kk < 12) ? btag[kk] : 0.0f;
  } else if (i < 10256 + 131072) {
    ws[OFF_PUB + (i - 10256)] = 0.0f;  // zero tags: no false-match vs any step tag
  }
}

// ---------------- fused recurrent LSTM: 8-way unit-split, reg weights, in-kernel x-proj ----------------
// R7 structure (known-good). R9 single change: keep-alive asm on wh[]/wi[] at the
// top of the step loop. R7's VGPR_Count=128 proved the compiler sank the Wih slice
// and re-streamed 128 KB/WG/step from L2 (~2000 cy of un-hidable bandwidth). The
// asm use at the loop head makes all weight regs live across the backedge, forcing
// true register residency (cap 256 via launch_bounds(512,2); LDS pad already
// limits to 1 WG/CU so the extra regs cost no occupancy).
#define FMA4(A, W, S) { A.x = fmaf(W.x, S, A.x); A.y = fmaf(W.y, S, A.y); \
                        A.z = fmaf(W.z, S, A.z); A.w = fmaf(W.w, S, A.w); }
#define KEEP4(V) asm volatile("" :: "v"(V.x), "v"(V.y), "v"(V.z), "v"(V.w))
__global__ __launch_bounds__(512, 2) void k_lstm_split(
    const float* __restrict__ ws_c, const int* __restrict__ sentence,
    const float* __restrict__ emb, const float* __restrict__ h0p,
    const float* __restrict__ c0p, const int* __restrict__ seq_lens,
    float* __restrict__ ws_mut, int first) {
  __shared__ float zpart[8][4][128];  // 16 KB: per-wave k-partials
  __shared__ float zs[4][128];        // 2 KB: summed z + bias
  __shared__ float h_s[4][256];       // 4 KB: gathered full h
  __shared__ float x_s[2][4][256];    // 8 KB: ping-pong emb rows
  __shared__ int   sent_s[4][1024];   // 16 KB: token ids for the quad
  __shared__ float ldspad[10240];     // 40 KB pad -> ~86 KB total, 1 WG/CU

  int bx = blockIdx.x;
  int w   = (bx >> 3) & 7;                 // unit-slice 0..7
  int gid = (bx & 7) + ((bx >> 6) << 3);   // group 0..31; 8 slices share an XCD (heuristic)
  int d   = gid >> 4;                      // dir
  int bq4 = (gid & 15) * 4;                // first batch of the quad
  int u0  = w * 32;                        // first owned unit
  int tid = threadIdx.x;
  if (first == 777) {  // opaque: keeps ldspad allocated, never taken at runtime
    ldspad[tid] = (float)tid; __syncthreads(); zs[0][0] = ldspad[tid ^ 1];
  }

  int cg = tid & 31, kq = tid >> 5;   // phase-A mapping: 4 cols x 16-k slice
  int c4 = cg * 4;
  int wv = tid >> 6, ln = tid & 63;

  for (int i = tid; i < 4096; i += 512)
    sent_s[i >> 10][i & 1023] = sentence[(size_t)(bq4 + (i >> 10)) * 1024 + (i & 1023)];
  __syncthreads();  // sent_s ready

  // ---- Whh + Wih slices into registers: 16 float4 each, fixed across all steps ----
  const float* WhhT = ws_c + OFF_WT_HH + (size_t)d * 262144;  // [256][1024]
  const float* WihT = ws_c + OFF_WT_IH + (size_t)d * 262144;
  int wcol = (cg >> 3) * 256 + u0 + (cg & 7) * 4;
  float4 wh[16], wi[16];
#pragma unroll
  for (int i = 0; i < 16; ++i) {
    wh[i] = *(const float4*)(WhhT + (size_t)(kq * 16 + i) * 1024 + wcol);
    wi[i] = *(const float4*)(WihT + (size_t)(kq * 16 + i) * 1024 + wcol);
  }

  for (int i = tid; i < 1024; i += 512) {
    int b = i >> 8, u = i & 255;
    h_s[b][u] = h0p[((size_t)d * 64 + bq4 + b) * 256 + u];
  }
  float cc = 0.0f; int mylen = 0;
  int ob = tid >> 5, ou = tid & 31;  // owner mapping (tid<128): (batch, owned unit)
  if (tid < 128) {
    cc = c0p[((size_t)d * 64 + bq4 + ob) * 256 + u0 + ou];
    mylen = seq_lens[bq4 + ob];
  }
  // phase-B col + bias (fixed per thread)
  int bB = tid >> 7, jB = tid & 127;
  int colB = ((jB >> 5) << 8) + u0 + (jB & 31);
  float biasB = ws_c[OFF_BIAS + (size_t)d * 1024 + colB];
  // x-load mapping: thread loads 2 floats of batch xb's emb row
  int xb = tid >> 7, xj = (tid & 127) * 2;
  {
    int tt = d ? 1023 : 0;
    float2 v = *(const float2*)(emb + (size_t)sent_s[xb][tt] * 256 + xj);
    x_s[0][xb][xj] = v.x; x_s[0][xb][xj + 1] = v.y;
  }
  // tag-head mapping (conflict-free: j stride-8 banks)
  int tb_b = wv >> 1;
  int tb_k = (wv & 1) * 8 + (ln >> 3);
  int tb_j = ln & 7;
  float wtag_r[32];
  {
    const float* wtg = ws_c + OFF_WTAGD + (size_t)d * 4096 + tb_k * 256;
#pragma unroll
    for (int i = 0; i < 32; ++i) wtag_r[i] = wtg[tb_j + 8 * i];
  }
  unsigned long long* pub64 = (unsigned long long*)(ws_mut + OFF_PUB);
  float* featsD = ws_mut + OFF_FEATS + (size_t)d * 1048576;
  int gb = tid >> 8, gu = tid & 255;  // gather mapping (2 elems/thread)
  bool bail = false;
  __syncthreads();  // h_s, x_s[0] ready

  // ---- pre-loop: x-projection partial for step 0 ----
  float4 acc_carry[4] = {{0,0,0,0},{0,0,0,0},{0,0,0,0},{0,0,0,0}};
#pragma unroll
  for (int i = 0; i < 4; ++i) {
    int k = kq * 16 + i * 4;
    float4 q0 = wi[i * 4], q1 = wi[i * 4 + 1], q2 = wi[i * 4 + 2], q3 = wi[i * 4 + 3];
#pragma unroll
    for (int b = 0; b < 4; ++b) {
      float4 xv = *(const float4*)&x_s[0][b][k];
      FMA4(acc_carry[b], q0, xv.x); FMA4(acc_carry[b], q1, xv.y);
      FMA4(acc_carry[b], q2, xv.z); FMA4(acc_carry[b], q3, xv.w);
    }
  }

  for (int s = 0; s < 1024; ++s) {
    // keep-alive: force wh/wi live across the loop backedge (defeats the
    // sink-to-shadow reload that R7's VGPR=128 exposed; rule #17 idiom)
#pragma unroll
    for (int i = 0; i < 16; ++i) { KEEP4(wh[i]); KEEP4(wi[i]); }
    int t = d ? (1023 - s) : s;
    int p = s & 1;
    int nxt = (s & 1) ^ 1;
    unsigned tag = (unsigned)(s + 1);
    // issue emb prefetch for step s+1 (consumed in phase B write; full-phase-A cover)
    float2 xpf;
    {
      int sn = (s + 1 < 1024) ? (s + 1) : s;
      int tn = d ? (1023 - sn) : sn;
      xpf = *(const float2*)(emb + (size_t)sent_s[xb][tn] * 256 + xj);
    }
    // ---- phase A: h-recurrence partials on top of the x-part (acc_carry) ----
    float4 acc[4];
#pragma unroll
    for (int b = 0; b < 4; ++b) acc[b] = acc_carry[b];
#pragma unroll
    for (int i = 0; i < 4; ++i) {
      int k = kq * 16 + i * 4;
      float4 w0 = wh[i * 4], w1 = wh[i * 4 + 1], w2 = wh[i * 4 + 2], w3 = wh[i * 4 + 3];
#pragma unroll
      for (int b = 0; b < 4; ++b) {
        float4 hv = *(const float4*)&h_s[b][k];
        FMA4(acc[b], w0, hv.x); FMA4(acc[b], w1, hv.y);
        FMA4(acc[b], w2, hv.z); FMA4(acc[b], w3, hv.w);
      }
    }
#pragma unroll
    for (int b = 0; b < 4; ++b) {  // fold the two k-slices within each wave
      acc[b].x += __shfl_xor(acc[b].x, 32);
      acc[b].y += __shfl_xor(acc[b].y, 32);
      acc[b].z += __shfl_xor(acc[b].z, 32);
      acc[b].w += __shfl_xor(acc[b].w, 32);
    }
    if ((tid & 32) == 0) {
#pragma unroll
      for (int b = 0; b < 4; ++b) *(float4*)&zpart[wv][b][c4] = acc[b];
    }
    __syncthreads();  // S1
    // ---- phase B: fold 8 wave-partials + bias; stage next x into x_s ----
    zs[bB][jB] = zpart[0][bB][jB] + zpart[1][bB][jB] + zpart[2][bB][jB] + zpart[3][bB][jB] +
                 zpart[4][bB][jB] + zpart[5][bB][jB] + zpart[6][bB][jB] + zpart[7][bB][jB] + biasB;
    x_s[nxt][xb][xj] = xpf.x; x_s[nxt][xb][xj + 1] = xpf.y;
    __syncthreads();  // S2
    // ---- phase C: owners update c/h; publish (tag|h) u64 ----
    if (tid < 128) {
      float zi = zs[ob][ou], zf = zs[ob][32 + ou], zg = zs[ob][64 + ou], zo = zs[ob][96 + ou];
      float cn = sigf(zf) * cc + sigf(zi) * tanhf(zg);
      float hn = sigf(zo) * tanhf(cn);
      bool m = t < mylen;
      cc = m ? cn : cc;
      float hp = m ? hn : h_s[ob][u0 + ou];
      union { float f; unsigned u; } hb; hb.f = hp;
      unsigned long long pk = ((unsigned long long)tag << 32) | (unsigned long long)hb.u;
      __hip_atomic_store(
          pub64 + (size_t)p * 32768 + ((size_t)d * 64 + bq4 + ob) * 256 + (u0 + ou),
          pk, __ATOMIC_RELAXED, __HIP_MEMORY_SCOPE_AGENT);
    }
    // ---- publish shadow: tag head for step s-1 from h_s (still h[s-1]) ----
    if (s > 0) {
      int tp = d ? (1023 - (s - 1)) : (s - 1);
      float pv = 0.0f;
#pragma unroll
      for (int i = 0; i < 32; ++i)
        pv = fmaf(h_s[tb_b][tb_j + 8 * i], wtag_r[i], pv);
      pv += __shfl_xor(pv, 1);
      pv += __shfl_xor(pv, 2);
      pv += __shfl_xor(pv, 4);
      if (w == 0 && tb_j == 0)
        featsD[(size_t)(bq4 + tb_b) * 16384 + (size_t)tp * 16 + tb_k] = pv;
    }
    __syncthreads();  // S3: tag-head reads of h_s done before gather overwrites
    // ---- gather: issue poll loads, fill RTT with next step's x-projection, then poll ----
    {
      size_t base = (size_t)p * 32768 + ((size_t)d * 64 + bq4) * 256;
      size_t i0 = base + (size_t)gb * 256 + gu;
      size_t i1 = i0 + 512;  // (gb+2)*256 + gu
      unsigned long long v0 =
          __hip_atomic_load(pub64 + i0, __ATOMIC_RELAXED, __HIP_MEMORY_SCOPE_AGENT);
      unsigned long long v1 =
          __hip_atomic_load(pub64 + i1, __ATOMIC_RELAXED, __HIP_MEMORY_SCOPE_AGENT);
      if (s + 1 < 1024) {  // x-projection for step s+1 from x_s[nxt], in the RTT shadow
#pragma unroll
        for (int b = 0; b < 4; ++b) { acc_carry[b].x = 0; acc_carry[b].y = 0;
                                      acc_carry[b].z = 0; acc_carry[b].w = 0; }
#pragma unroll
        for (int i = 0; i < 4; ++i) {
          int k = kq * 16 + i * 4;
          float4 q0 = wi[i * 4], q1 = wi[i * 4 + 1], q2 = wi[i * 4 + 2], q3 = wi[i * 4 + 3];
#pragma unroll
          for (int b = 0; b < 4; ++b) {
            float4 xv = *(const float4*)&x_s[nxt][b][k];
            FMA4(acc_carry[b], q0, xv.x); FMA4(acc_carry[b], q1, xv.y);
            FMA4(acc_carry[b], q2, xv.z); FMA4(acc_carry[b], q3, xv.w);
          }
        }
      }
      unsigned spin = 0;
      while ((((unsigned)(v0 >> 32) != tag) || ((unsigned)(v1 >> 32) != tag)) && !bail) {
        __builtin_amdgcn_s_sleep(1);
        if ((unsigned)(v0 >> 32) != tag)
          v0 = __hip_atomic_load(pub64 + i0, __ATOMIC_RELAXED, __HIP_MEMORY_SCOPE_AGENT);
        if ((unsigned)(v1 >> 32) != tag)
          v1 = __hip_atomic_load(pub64 + i1, __ATOMIC_RELAXED, __HIP_MEMORY_SCOPE_AGENT);
        if (++spin > 2000000u) { bail = true; break; }  // sticky escape: finite fail
      }
      union { unsigned u32; float f; } cv0, cv1;
      cv0.u32 = (unsigned)v0; cv1.u32 = (unsigned)v1;
      h_s[gb][gu]     = cv0.f;
      h_s[gb + 2][gu] = cv1.f;
    }
    __syncthreads();  // S4
  }
  // drain: tag head for the last step from final gathered h
  {
    float pv = 0.0f;
#pragma unroll
    for (int i = 0; i < 32; ++i)
      pv = fmaf(h_s[tb_b][tb_j + 8 * i], wtag_r[i], pv);
    pv += __shfl_xor(pv, 1);
    pv += __shfl_xor(pv, 2);
    pv += __shfl_xor(pv, 4);
    int tl = d ? 0 : 1023;
    if (w == 0 && tb_j == 0)
      featsD[(size_t)(bq4 + tb_b) * 16384 + (size_t)tl * 16 + tb_k] = pv;
  }
}

// ---------------- fallback fused LSTM (round-2, known-good; tiny-workspace path) ----------------
__global__ __launch_bounds__(256) void k_lstm_fused(
    const float* __restrict__ ws_c, const int* __restrict__ sentence,
    const float* __restrict__ emb, const float* __restrict__ h0p,
    const float* __restrict__ c0p, const int* __restrict__ seq_lens,
    float* __restrict__ ws_mut) {
  int d = blockIdx.x & 1;
  int pr = blockIdx.x >> 1;
  int b0 = pr * 2, b1 = b0 + 1;
  const float* Wih = ws_c + OFF_WT_IH + (size_t)d * 262144;
  const float* Whh = ws_c + OFF_WT_HH + (size_t)d * 262144;
  __shared__ float h_s[2][256];
  __shared__ float x_s[2][2][256];
  __shared__ float z_s[2][1024];
  __shared__ int   sent_s[2][1024];
  __shared__ float wt_s[16][260];
  __shared__ float pfp_s[2][16][8];
  int tid = threadIdx.x;
  int len0 = seq_lens[b0], len1 = seq_lens[b1];
  for (int i = tid; i < 2048; i += 256)
    sent_s[i >> 10][i & 1023] = sentence[(size_t)(b0 + (i >> 10)) * 1024 + (i & 1023)];
  for (int i = tid; i < 4096; i += 256)
    wt_s[i >> 8][i & 255] = ws_c[OFF_WTAGD + (size_t)d * 4096 + i];
  h_s[0][tid] = h0p[((size_t)d * 64 + b0) * 256 + tid];
  h_s[1][tid] = h0p[((size_t)d * 64 + b1) * 256 + tid];
  float cc0 = c0p[((size_t)d * 64 + b0) * 256 + tid];
  float cc1 = c0p[((size_t)d * 64 + b1) * 256 + tid];
  int c4 = tid * 4;
  float4 bias_v = *(const float4*)(ws_c + OFF_BIAS + (size_t)d * 1024 + c4);
  __syncthreads();
  int t0 = d ? 1023 : 0;
  if (tid < 128) {
    int bb = tid >> 6, l = tid & 63;
    int row = sent_s[bb][t0];
    *(float4*)&x_s[0][bb][l * 4] = *(const float4*)(emb + (size_t)row * 256 + l * 4);
  }
  __syncthreads();
  float* featsD = ws_mut + OFF_FEATS + (size_t)d * 1048576;
  for (int s = 0; s < 1024; ++s) {
    int t = d ? (1023 - s) : s;
    int cur = s & 1, nxt = cur ^ 1;
    float4 pf = {0, 0, 0, 0};
    if (tid < 128) {
      int sn = (s < 1023) ? (s + 1) : 1023;
      int tn = d ? (1023 - sn) : sn;
      int bb = tid >> 6, l = tid & 63;
      pf = *(const float4*)(emb + (size_t)sent_s[bb][tn] * 256 + l * 4);
    }
    float4 a0 = bias_v, a1 = bias_v;
#pragma unroll 4
    for (int k = 0; k < 256; k += 4) {
      float4 xv0 = *(const float4*)&x_s[cur][0][k];
      float4 xv1 = *(const float4*)&x_s[cur][1][k];
      float4 hv0 = *(const float4*)&h_s[0][k];
      float4 hv1 = *(const float4*)&h_s[1][k];
      const float* wi = Wih + (size_t)k * 1024 + c4;
      const float* wh = Whh + (size_t)k * 1024 + c4;
      float4 wi0 = *(const float4*)(wi);
      float4 wi1 = *(const float4*)(wi + 1024);
      float4 wi2 = *(const float4*)(wi + 2048);
      float4 wi3 = *(const float4*)(wi + 3072);
      float4 wh0 = *(const float4*)(wh);
      float4 wh1 = *(const float4*)(wh + 1024);
      float4 wh2 = *(const float4*)(wh + 2048);
      float4 wh3 = *(const float4*)(wh + 3072);
      FMA4(a0, wi0, xv0.x); FMA4(a0, wi1, xv0.y); FMA4(a0, wi2, xv0.z); FMA4(a0, wi3, xv0.w);
      FMA4(a0, wh0, hv0.x); FMA4(a0, wh1, hv0.y); FMA4(a0, wh2, hv0.z); FMA4(a0, wh3, hv0.w);
      FMA4(a1, wi0, xv1.x); FMA4(a1, wi1, xv1.y); FMA4(a1, wi2, xv1.z); FMA4(a1, wi3, xv1.w);
      FMA4(a1, wh0, hv1.x); FMA4(a1, wh1, hv1.y); FMA4(a1, wh2, hv1.z); FMA4(a1, wh3, hv1.w);
    }
    *(float4*)&z_s[0][c4] = a0;
    *(float4*)&z_s[1][c4] = a1;
    __syncthreads();
    {
      float iv = z_s[0][tid], fv = z_s[0][tid + 256];
      float gv = z_s[0][tid + 512], ov = z_s[0][tid + 768];
      float cn = sigf(fv) * cc0 + sigf(iv) * tanhf(gv);
      float hn = sigf(ov) * tanhf(cn);
      bool m = t < len0;
      cc0 = m ? cn : cc0;
      h_s[0][tid] = m ? hn : h_s[0][tid];
    }
    {
      float iv = z_s[1][tid], fv = z_s[1][tid + 256];
      float gv = z_s[1][tid + 512], ov = z_s[1][tid + 768];
      float cn = sigf(fv) * cc1 + sigf(iv) * tanhf(gv);
      float hn = sigf(ov) * tanhf(cn);
      bool m = t < len1;
      cc1 = m ? cn : cc1;
      h_s[1][tid] = m ? hn : h_s[1][tid];
    }
    if (tid < 128) {
      int bb = tid >> 6, l = tid & 63;
      *(float4*)&x_s[nxt][bb][l * 4] = pf;
    }
    __syncthreads();
    {
      int b2 = tid >> 7, r = tid & 127;
      int ks = r >> 3, jg = r & 7;
      const float* hv = &h_s[b2][jg * 32];
      const float* wv = &wt_s[ks][jg * 32];
      float p = 0.0f;
#pragma unroll
      for (int i = 0; i < 32; ++i) p = fmaf(hv[i], wv[i], p);
      pfp_s[b2][ks][jg] = p;
    }
    __syncthreads();
    if (tid < 32) {
      int b = tid >> 4, k = tid & 15;
      float sum = 0.0f;
#pragma unroll
      for (int i = 0; i < 8; ++i) sum += pfp_s[b][k][i];
      featsD[(size_t)(b0 + b) * 16384 + (size_t)t * 16 + k] = sum;
    }
  }
}

// ---------------- Viterbi + backtrace, one wave per batch element ----------------
__global__ __launch_bounds__(64) void k_viterbi(const float* __restrict__ ws_c,
                                                const float* __restrict__ trans,
                                                const int* __restrict__ seq_lens,
                                                float* __restrict__ out) {
  __shared__ char bp_s[1024][12];
  int b = blockIdx.x, lane = threadIdx.x;
  int len = seq_lens[b];
  float trow[12];
#pragma unroll
  for (int p = 0; p < 12; ++p) trow[p] = (lane < 12) ? trans[lane * 12 + p] : 0.0f;
  float tb = (lane < 16) ? ws_c[OFF_BTAG + lane] : 0.0f;
  float fv = (lane == 10) ? 0.0f : NEG10K;  // START=10
  const float* ff = ws_c + OFF_FEATS + (size_t)b * 16384;
  const float* fb = ws_c + OFF_FEATS + 1048576 + (size_t)b * 16384;
  for (int t = 0; t < 1024; ++t) {
    float ft = (lane < 16) ? (ff[t * 16 + lane] + fb[t * 16 + lane] + tb) : 0.0f;
    float best = -3.0e38f; int arg = 0;
#pragma unroll
    for (int p = 0; p < 12; ++p) {
      float s = __shfl(fv, p) + trow[p];
      if (s > best) { best = s; arg = p; }
    }
    bool m = t < len;
    if (m) fv = best + ft;
    if (lane < 12) bp_s[t][lane] = (char)(m ? arg : lane);
  }
  float term = (lane < 12) ? fv + trans[132 + lane] : -3.0e38f;  // STOP row = 11
  float bestv = -3.0e38f; int bestp = 0;
#pragma unroll
  for (int p = 0; p < 12; ++p) {
    float v = __shfl(term, p);
    if (v > bestv) { bestv = v; bestp = p; }
  }
  __syncthreads();
  if (lane == 0) {
    out[b] = bestv;
    int tag = bestp;
    float* po = out + 64 + (size_t)b * 1024;
    for (int t = 1023; t >= 0; --t) {
      po[t] = (t < len) ? (float)tag : 0.0f;
      tag = bp_s[t][tag];
    }
  }
}

extern "C" void kernel_launch(void* const* d_in, const int* in_sizes, int n_in,
                              void* d_out, int out_size, void* d_ws, size_t ws_size,
                              hipStream_t stream) {
  (void)in_sizes; (void)n_in; (void)out_size;
  const int*   sentence = (const int*)d_in[0];
  const int*   seq_lens = (const int*)d_in[1];
  const float* emb      = (const float*)d_in[2];
  const float* wih_f    = (const float*)d_in[3];
  const float* whh_f    = (const float*)d_in[4];
  const float* bih_f    = (const float*)d_in[5];
  const float* bhh_f    = (const float*)d_in[6];
  const float* wih_b    = (const float*)d_in[7];
  const float* whh_b    = (const float*)d_in[8];
  const float* bih_b    = (const float*)d_in[9];
  const float* bhh_b    = (const float*)d_in[10];
  const float* wtag     = (const float*)d_in[11];
  const float* btag     = (const float*)d_in[12];
  const float* trans    = (const float*)d_in[13];
  const float* h0p      = (const float*)d_in[14];
  const float* c0p      = (const float*)d_in[15];
  float* ws  = (float*)d_ws;
  float* out = (float*)d_out;
  size_t avail = ws_size / 4;
  if (avail < OFF_FEATS + 2097152) return;  // below even the fused path's needs

  k_transpose<<<dim3(8, 32, 4), 256, 0, stream>>>(wih_f, wih_b, whh_f, whh_b, ws);
  k_prep_small<<<553, 256, 0, stream>>>(bih_f, bhh_f, bih_b, bhh_b, wtag, btag, ws);
  if (avail >= OFF_END) {
    k_lstm_split<<<256, 512, 0, stream>>>(ws, sentence, emb, h0p, c0p, seq_lens, ws, 1);
  } else {
    k_lstm_fused<<<64, 256, 0, stream>>>(ws, sentence, emb, h0p, c0p, seq_lens, ws);
  }
  k_viterbi<<<64, 64, 0, stream>>>(ws, trans, seq_lens, out);
}